// Round 1
// baseline (219.928 us; speedup 1.0000x reference)
//
#include <hip/hip_runtime.h>

typedef unsigned short u16;
typedef unsigned int u32;
typedef __attribute__((ext_vector_type(8))) short short8;
typedef __attribute__((ext_vector_type(4))) float f32x4;

#define DEV static __device__ __forceinline__

DEV float bf2f(u16 u){ u32 i = ((u32)u)<<16; float f; __builtin_memcpy(&f,&i,4); return f; }
DEV u16 f2bf(float f){ u32 i; __builtin_memcpy(&i,&f,4); u32 r = i + 0x7FFFu + ((i>>16)&1u); return (u16)(r>>16); }

DEV void gld16(const void* gp, void* lp){
  __builtin_amdgcn_global_load_lds((const __attribute__((address_space(1))) void*)gp,
                                   (__attribute__((address_space(3))) void*)lp, 16, 0, 0);
}

// ---------------- utility kernels ----------------

__global__ void k_zero(float* s){ if (threadIdx.x < 64) s[threadIdx.x] = 0.f; }

__global__ void k_cvt_x(const float* __restrict__ x, u16* __restrict__ xb){
  size_t base = ((size_t)blockIdx.x*256 + threadIdx.x)*4;
  float4 v = *(const float4*)(x + base);
  u16 o0=f2bf(v.x), o1=f2bf(v.y), o2=f2bf(v.z), o3=f2bf(v.w);
  ushort4 o; o.x=o0; o.y=o1; o.z=o2; o.w=o3;
  *(ushort4*)(xb + base) = o;
}

// src: K x N fp32 row-major  ->  dst: N x K bf16 row-major
__global__ void k_wtrans(const float* __restrict__ src, u16* __restrict__ dst, int N, int K){
  __shared__ float tile[32][33];
  int n0 = blockIdx.x*32, k0 = blockIdx.y*32;
  int tx = threadIdx.x, ty = threadIdx.y;
  #pragma unroll
  for (int i=0;i<4;++i)
    tile[ty + i*8][tx] = src[(size_t)(k0 + ty + i*8)*N + n0 + tx];
  __syncthreads();
  #pragma unroll
  for (int i=0;i<4;++i)
    dst[(size_t)(n0 + ty + i*8)*K + k0 + tx] = f2bf(tile[tx][ty + i*8]);
}

// Vraw [4096][1536] bf16 -> VbT [(bh)*256+v][2048] bf16
__global__ void k_vtrans(const u16* __restrict__ Vraw, u16* __restrict__ VbT){
  __shared__ u16 tile[32][33];
  int bh = blockIdx.z, b = bh/6, h = bh%6;
  int t0 = blockIdx.x*32, v0 = blockIdx.y*32;
  int tx = threadIdx.x, ty = threadIdx.y;
  #pragma unroll
  for (int i=0;i<4;++i)
    tile[ty+i*8][tx] = Vraw[(size_t)(b*2048 + t0 + ty + i*8)*1536 + h*256 + v0 + tx];
  __syncthreads();
  #pragma unroll
  for (int i=0;i<4;++i)
    VbT[(size_t)(bh*256 + v0 + ty + i*8)*2048 + t0 + tx] = tile[tx][ty+i*8];
}

// xPos rotary, in place on [4096][768] bf16 (cols = h*128 + d)
__global__ void k_xpos(u16* __restrict__ P, float sign){
  int idx = blockIdx.x*256 + threadIdx.x;   // (m*6 + h)*64 + j
  int j  = idx & 63;
  int mh = idx >> 6;
  int h  = mh % 6;
  int m  = mh / 6;
  int t  = m & 2047;
  float inv_freq = expf(-(float)j * (9.210340371976184f/64.f)); // 10000^(-j/64)
  float angle = (float)t * inv_freq;
  float zeta = (float)(j + 64) * (1.f/128.f);
  float dec = exp2f(log2f(zeta) * (sign*(float)t*(1.f/512.f)));
  float sn, cs;
  sincosf(angle, &sn, &cs);
  cs *= dec; sn *= dec;
  size_t base = (size_t)m*768 + h*128 + j;
  float x1 = bf2f(P[base]), x2 = bf2f(P[base+64]);
  P[base]    = f2bf(x1*cs - x2*sn);
  P[base+64] = f2bf(x1*sn + x2*cs);
}

// ---------------- GEMM: C[M,N] = A[M,K] * BT[N,K]^T  (bf16 in, fp32 acc) ----------------
// MODE 0: fused QKVG epilogue (bf16 outs, silu on G region). MODE 1: fp32 out.
template<int MODE>
__global__ __launch_bounds__(256)
void k_gemm(const u16* __restrict__ A, const u16* __restrict__ BT,
            int K, int N,
            u16* __restrict__ Qr, u16* __restrict__ Kr,
            u16* __restrict__ Vraw, u16* __restrict__ Gb,
            float* __restrict__ Out)
{
  __shared__ u16 As[128*64];
  __shared__ u16 Bs[128*64];
  const int tid = threadIdx.x;
  const int w = tid>>6, l = tid&63, g = l>>4, ln = l&15;
  const int wr = w>>1, wc = w&1;
  const int m0 = blockIdx.x*128, n0 = blockIdx.y*128;
  const f32x4 fz = {0.f,0.f,0.f,0.f};
  f32x4 acc[4][4];
  #pragma unroll
  for (int m=0;m<4;++m)
    #pragma unroll
    for (int n=0;n<4;++n) acc[m][n] = fz;

  const int nk = K>>6;
  for (int kt=0; kt<nk; ++kt){
    const int k0 = kt<<6;
    #pragma unroll
    for (int i=0;i<4;++i){
      int off = i*4096 + tid*16;
      int row = off>>7;                       // 128B per row
      int colb = (((off>>4)&7)<<4) ^ ((row&7)<<4);
      gld16(A  + (size_t)(m0+row)*K + k0 + (colb>>1), (char*)As + i*4096 + w*1024);
      gld16(BT + (size_t)(n0+row)*K + k0 + (colb>>1), (char*)Bs + i*4096 + w*1024);
    }
    __syncthreads();
    #pragma unroll
    for (int kk=0;kk<2;++kk){
      short8 a[4], b[4];
      #pragma unroll
      for (int m=0;m<4;++m){
        int row = wr*64 + m*16 + ln;
        int byte = row*128 + ((kk*64 + g*16) ^ ((row&7)<<4));
        a[m] = *(const short8*)((const char*)As + byte);
      }
      #pragma unroll
      for (int n=0;n<4;++n){
        int row = wc*64 + n*16 + ln;
        int byte = row*128 + ((kk*64 + g*16) ^ ((row&7)<<4));
        b[n] = *(const short8*)((const char*)Bs + byte);
      }
      #pragma unroll
      for (int m=0;m<4;++m)
        #pragma unroll
        for (int n=0;n<4;++n)
          acc[m][n] = __builtin_amdgcn_mfma_f32_16x16x32_bf16(a[m], b[n], acc[m][n], 0,0,0);
    }
    __syncthreads();
  }
  // epilogue
  const int region = n0/768;  // tile never crosses a 768 boundary
  #pragma unroll
  for (int m=0;m<4;++m){
    int grow0 = m0 + wr*64 + m*16 + g*4;
    #pragma unroll
    for (int n=0;n<4;++n){
      int c = n0 + wc*64 + n*16 + ln;
      #pragma unroll
      for (int r=0;r<4;++r){
        float v = acc[m][n][r];
        size_t grow = (size_t)(grow0 + r);
        if (MODE == 1){
          Out[grow*(size_t)N + c] = v;
        } else {
          if (region==0)      Qr[grow*768 + c] = f2bf(v);
          else if (region==1) Kr[grow*768 + (c-768)] = f2bf(v);
          else if (region<4)  Vraw[grow*1536 + (c-1536)] = f2bf(v);
          else { float sg = v/(1.f+__expf(-v)); Gb[grow*1536 + (c-3072)] = f2bf(sg); }
        }
      }
    }
  }
}

// ---------------- retention (flash-style, causal decay) ----------------
// grid (32, 12): blockIdx.x -> qb (reversed), blockIdx.y -> bh. 256 thr = 4 waves, 16 q-rows each.
__global__ __launch_bounds__(256)
void k_ret(const u16* __restrict__ Qb, const u16* __restrict__ Kb,
           const u16* __restrict__ VbT, float* __restrict__ Of, float* __restrict__ stats)
{
  __shared__ u16 Ks[64*128];    // 16 KB, swizzled
  __shared__ u16 Vt[256*64];    // 32 KB, V^T tile [v][key], swizzled
  __shared__ float Ps[64*64];   // 16 KB, swizzled
  const int tid = threadIdx.x, w = tid>>6, l = tid&63, g = l>>4, ln = l&15;
  const int qb = (int)gridDim.x - 1 - (int)blockIdx.x;
  const int bh = blockIdx.y, b = bh/6, h = bh%6;
  const float omg = exp2f(-(float)(5+h));   // 1-gamma (exact)
  const float gamma = 1.f - omg;
  const float lg2g = log2f(gamma);
  const float scale = 0.08838834764831845f; // 128^-0.5
  const int q0 = qb*64;
  const f32x4 fz = {0.f,0.f,0.f,0.f};

  short8 aq[4];
  {
    const size_t qrow = (size_t)(b*2048 + q0 + w*16 + ln)*768 + h*128;
    #pragma unroll
    for (int kk=0;kk<4;++kk) aq[kk] = *(const short8*)(Qb + qrow + kk*32 + g*8);
  }
  f32x4 accO[16];
  #pragma unroll
  for (int i=0;i<16;++i) accO[i] = fz;

  for (int kb=0; kb<=qb; ++kb){
    #pragma unroll
    for (int i=0;i<4;++i){   // K tile: 64 rows x 128 d
      int off = i*4096 + tid*16;
      int row = off>>8;      // 256B rows
      int colb = (((off>>4)&15)<<4) ^ ((row&7)<<4);
      gld16(Kb + (size_t)(b*2048 + kb*64 + row)*768 + h*128 + (colb>>1),
            (char*)Ks + i*4096 + w*1024);
    }
    #pragma unroll
    for (int i=0;i<8;++i){   // V^T tile: 256 rows(v) x 64 keys
      int off = i*4096 + tid*16;
      int row = off>>7;      // 128B rows
      int colb = (((off>>4)&7)<<4) ^ ((row&7)<<4);
      gld16(VbT + (size_t)(bh*256 + row)*2048 + kb*64 + (colb>>1),
            (char*)Vt + i*4096 + w*1024);
    }
    __syncthreads();

    // S = Q K^T (wave's 16 q-rows x 64 keys)
    f32x4 s[4]; s[0]=fz; s[1]=fz; s[2]=fz; s[3]=fz;
    #pragma unroll
    for (int kk=0;kk<4;++kk){
      #pragma unroll
      for (int n=0;n<4;++n){
        int row = n*16 + ln;
        int byte = row*256 + ((kk*64 + g*16) ^ ((row&7)<<4));
        short8 bk = *(const short8*)((const char*)Ks + byte);
        s[n] = __builtin_amdgcn_mfma_f32_16x16x32_bf16(aq[kk], bk, s[n], 0,0,0);
      }
    }
    // decay + scale -> Ps (fp32, swizzled)
    const int kj0 = kb*64;
    #pragma unroll
    for (int n=0;n<4;++n){
      int kj = kj0 + n*16 + ln;
      #pragma unroll
      for (int r=0;r<4;++r){
        int qi = q0 + w*16 + g*4 + r;
        int d = qi - kj;
        float p = 0.f;
        if (d >= 0) p = s[n][r] * scale * exp2f(lg2g*(float)d);
        int prow = w*16 + g*4 + r;
        int byte = prow*256 + ((((n*16+ln)*4)) ^ ((prow&7)<<4));
        *(float*)((char*)Ps + byte) = p;
      }
    }
    // PV (wave-local rows of Ps; same-wave write->read ordered by compiler)
    #pragma unroll
    for (int kk2=0;kk2<2;++kk2){
      int prow = w*16 + ln;
      int base = prow*256;
      int c0 = kk2*128 + g*32;
      int sw = (prow&7)<<4;
      f32x4 p0 = *(const f32x4*)((const char*)Ps + base + ((c0   )^sw));
      f32x4 p1 = *(const f32x4*)((const char*)Ps + base + ((c0+16)^sw));
      short8 ap;
      #pragma unroll
      for (int jj=0;jj<4;++jj){ ap[jj] = (short)f2bf(p0[jj]); ap[4+jj] = (short)f2bf(p1[jj]); }
      #pragma unroll
      for (int n2=0;n2<16;++n2){
        int vrow = n2*16 + ln;
        int byte = vrow*128 + ((kk2*64 + g*16) ^ ((vrow&7)<<4));
        short8 bv = *(const short8*)((const char*)Vt + byte);
        accO[n2] = __builtin_amdgcn_mfma_f32_16x16x32_bf16(ap, bv, accO[n2], 0,0,0);
      }
    }
    __syncthreads();
  }

  // epilogue: rowsum normalize, store, groupnorm partial stats
  float inv4[4];
  #pragma unroll
  for (int r=0;r<4;++r){
    int qi = q0 + w*16 + g*4 + r;
    float rs = (1.f - exp2f(lg2g*(float)(qi+1))) / omg;
    inv4[r] = rsqrtf(fmaxf(rs, 1e-6f));
  }
  float lsum=0.f, lsq=0.f;
  #pragma unroll
  for (int n2=0;n2<16;++n2){
    #pragma unroll
    for (int r=0;r<4;++r){
      float v = accO[n2][r]*inv4[r];
      Of[(size_t)(b*2048 + q0 + w*16 + g*4 + r)*1536 + h*256 + n2*16 + ln] = v;
      lsum += v; lsq += v*v;
    }
  }
  #pragma unroll
  for (int o=32;o;o>>=1){ lsum += __shfl_xor(lsum,o,64); lsq += __shfl_xor(lsq,o,64); }
  if (l==0){ atomicAdd(&stats[bh*2], lsum); atomicAdd(&stats[bh*2+1], lsq); }
}

// ---------------- groupnorm + gate ----------------
__global__ void k_gatenorm(const float* __restrict__ Of, const u16* __restrict__ Gb,
                           const float* __restrict__ gnw, const float* __restrict__ gnb,
                           const float* __restrict__ stats, u16* __restrict__ Yb){
  size_t base = ((size_t)blockIdx.x*256 + threadIdx.x)*8;
  int m = (int)(base/1536);
  int c = (int)(base%1536);
  int bh = (m>>11)*6 + (c>>8);
  const float Ninv = 1.f/524288.f;
  float mean = stats[bh*2]*Ninv;
  float var = stats[bh*2+1]*Ninv - mean*mean;
  float rstd = rsqrtf(var + 1e-5f);
  #pragma unroll
  for (int jj=0;jj<8;++jj){
    float o = Of[base+jj];
    float nv = (o-mean)*rstd*gnw[c+jj] + gnb[c+jj];
    Yb[base+jj] = f2bf(nv * bf2f(Gb[base+jj]));
  }
}

// ---------------- launch ----------------
extern "C" void kernel_launch(void* const* d_in, const int* in_sizes, int n_in,
                              void* d_out, int out_size, void* d_ws, size_t ws_size,
                              hipStream_t stream)
{
  const float* x   = (const float*)d_in[0];
  const float* Wq  = (const float*)d_in[1];
  const float* Wk  = (const float*)d_in[2];
  const float* Wv  = (const float*)d_in[3];
  const float* Wg  = (const float*)d_in[4];
  const float* Wo  = (const float*)d_in[5];
  const float* gnw = (const float*)d_in[6];
  const float* gnb = (const float*)d_in[7];
  float* out = (float*)d_out;

  char* ws = (char*)d_ws;
  size_t off = 0;
  auto alloc = [&](size_t bytes){ char* p = ws + off; off += (bytes + 255) & ~(size_t)255; return p; };
  u16*  xb   = (u16*) alloc(4096ull*768*2);
  u16*  WT   = (u16*) alloc(4608ull*768*2);
  u16*  WoT  = (u16*) alloc(768ull*1536*2);
  u16*  Qr   = (u16*) alloc(4096ull*768*2);
  u16*  Kr   = (u16*) alloc(4096ull*768*2);
  u16*  Vraw = (u16*) alloc(4096ull*1536*2);
  u16*  VbT  = (u16*) alloc(4096ull*1536*2);
  u16*  Gb   = (u16*) alloc(4096ull*1536*2);
  float* Of  = (float*)alloc(4096ull*1536*4);
  u16*  Yb   = (u16*) alloc(4096ull*1536*2);
  float* stats = (float*)alloc(256);

  k_zero<<<1, 64, 0, stream>>>(stats);
  k_cvt_x<<<3072, 256, 0, stream>>>(x, xb);
  k_wtrans<<<dim3(24,24), dim3(32,8), 0, stream>>>(Wq, WT,             768, 768);
  k_wtrans<<<dim3(24,24), dim3(32,8), 0, stream>>>(Wk, WT + 768ull*768, 768, 768);
  k_wtrans<<<dim3(48,24), dim3(32,8), 0, stream>>>(Wv, WT + 1536ull*768, 1536, 768);
  k_wtrans<<<dim3(48,24), dim3(32,8), 0, stream>>>(Wg, WT + 3072ull*768, 1536, 768);
  k_wtrans<<<dim3(24,48), dim3(32,8), 0, stream>>>(Wo, WoT,             768, 1536);
  k_gemm<0><<<dim3(32,36), 256, 0, stream>>>(xb, WT, 768, 4608, Qr, Kr, Vraw, Gb, (float*)nullptr);
  k_xpos<<<6144, 256, 0, stream>>>(Qr,  1.f);
  k_xpos<<<6144, 256, 0, stream>>>(Kr, -1.f);
  k_vtrans<<<dim3(64,8,12), dim3(32,8), 0, stream>>>(Vraw, VbT);
  k_ret<<<dim3(32,12), 256, 0, stream>>>(Qr, Kr, VbT, Of, stats);
  k_gatenorm<<<3072, 256, 0, stream>>>(Of, Gb, gnw, gnb, stats, Yb);
  k_gemm<1><<<dim3(32,6), 256, 0, stream>>>(Yb, WoT, 1536, 768,
                                            (u16*)nullptr,(u16*)nullptr,(u16*)nullptr,(u16*)nullptr, out);
}